// Round 6
// baseline (448.286 us; speedup 1.0000x reference)
//
#include <hip/hip_runtime.h>
#include <cstdint>
#include <cstddef>

#define CC 128
#define LOG_FINE 7
#define FINE 128
#define CAPE 6144     // capacity per edge bucket (mean 4092, std ~64)
#define CAPV 3072     // capacity per node bucket (mean 2046, std ~45)
#define BIN_TILE 4096 // pairs per bin_both block

__device__ __forceinline__ unsigned f2b(float f) {
    const unsigned u = __float_as_uint(f);
    return (u + 0x7fffu + ((u >> 16) & 1u)) >> 16;
}
__device__ __forceinline__ float b2f_lo(unsigned u) { return __uint_as_float(u << 16); }
__device__ __forceinline__ float b2f_hi(unsigned u) { return __uint_as_float(u & 0xffff0000u); }

// ---------------- convert f32 -> bf16 (packed 2/uint) ----------------
__global__ __launch_bounds__(256) void to_bf16(const float4* __restrict__ in,
                                               uint2* __restrict__ out, int n4) {
    for (int i = blockIdx.x * 256 + threadIdx.x; i < n4; i += gridDim.x * 256) {
        const float4 v = in[i];
        out[i] = make_uint2(f2b(v.x) | (f2b(v.y) << 16), f2b(v.z) | (f2b(v.w) << 16));
    }
}

// ---------------- init bucket cursors to region bases ----------------
__global__ __launch_bounds__(256) void initcur(int* __restrict__ curE, int nbE,
                                               int* __restrict__ curV, int nbV) {
    const int i = blockIdx.x * 256 + threadIdx.x;
    if (i < nbE) curE[i] = i * CAPE;
    if (i < nbV) curV[i] = i * CAPV;
}

// ---------------- bin pairs into fixed-capacity bucket regions (both sides) ----------------
__global__ __launch_bounds__(256) void bin_both(const int* __restrict__ nidx,
                                                const int* __restrict__ eidx,
                                                int* __restrict__ curE,
                                                int* __restrict__ curV,
                                                unsigned* __restrict__ binnedE,
                                                unsigned* __restrict__ binnedV,
                                                int nnz, int nbE, int nbV) {
    __shared__ int cntE[512], gposE[512];
    __shared__ int cntV[1024], gposV[1024];
    const int tid = threadIdx.x;
    for (int i = tid; i < nbE; i += 256) cntE[i] = 0;
    for (int i = tid; i < nbV; i += 256) cntV[i] = 0;
    __syncthreads();
    const int base = blockIdx.x * BIN_TILE;
    int pE[16], rE[16], pV[16], rV[16];
#pragma unroll
    for (int j = 0; j < 16; ++j) {
        const int i = base + tid + j * 256;
        if (i < nnz) {
            const int e = eidx[i], v = nidx[i];
            const int bE = e >> LOG_FINE, bV = v >> LOG_FINE;
            rE[j] = (bE << 16) | atomicAdd(&cntE[bE], 1);
            pE[j] = (v << LOG_FINE) | (e & (FINE - 1));
            rV[j] = (bV << 16) | atomicAdd(&cntV[bV], 1);
            pV[j] = (e << LOG_FINE) | (v & (FINE - 1));
        } else { rE[j] = -1; rV[j] = -1; }
    }
    __syncthreads();
    for (int i = tid; i < nbE; i += 256) {
        const int c = cntE[i];
        gposE[i] = (c > 0) ? atomicAdd(&curE[i], c) : 0;
    }
    for (int i = tid; i < nbV; i += 256) {
        const int c = cntV[i];
        gposV[i] = (c > 0) ? atomicAdd(&curV[i], c) : 0;
    }
    __syncthreads();
#pragma unroll
    for (int j = 0; j < 16; ++j) {
        if (rE[j] >= 0) binnedE[gposE[rE[j] >> 16] + (rE[j] & 0xffff)] = (unsigned)pE[j];
        if (rV[j] >= 0) binnedV[gposV[rV[j] >> 16] + (rV[j] & 0xffff)] = (unsigned)pV[j];
    }
}

// ---------------- per-bucket fine counting-sort (in place) + row ranges ----------------
template <int CAP>
__global__ __launch_bounds__(512) void fill_fine(const int* __restrict__ cur,
                                                 unsigned* __restrict__ binned,
                                                 int2* __restrict__ rows, int nrows) {
    __shared__ unsigned vals[CAP];
    __shared__ int scnt[FINE], soff[FINE], sscan[FINE];
    const int tid = threadIdx.x;
    const int b = blockIdx.x;
    const int base = b * CAP;
    const int cnt = cur[b] - base;
    for (int i = tid; i < cnt; i += 512) vals[i] = binned[base + i];
    if (tid < FINE) scnt[tid] = 0;
    __syncthreads();
    for (int i = tid; i < cnt; i += 512) atomicAdd(&scnt[vals[i] & (FINE - 1)], 1);
    __syncthreads();
    if (tid < FINE) sscan[tid] = scnt[tid];
    __syncthreads();
#pragma unroll
    for (int d = 1; d < FINE; d <<= 1) {
        int t = 0;
        if (tid >= d && tid < FINE) t = sscan[tid - d];
        __syncthreads();
        if (tid < FINE) sscan[tid] += t;
        __syncthreads();
    }
    if (tid < FINE) {
        const int excl = sscan[tid] - scnt[tid];
        soff[tid] = excl;
        const int row = (b << LOG_FINE) + tid;
        if (row < nrows) rows[row] = make_int2(base + excl, base + excl + scnt[tid]);
    }
    __syncthreads();
    for (int i = tid; i < cnt; i += 512) {
        const unsigned p = vals[i];
        const int slot = (int)(p & (FINE - 1));
        const int pos = base + atomicAdd(&soff[slot], 1);
        binned[pos] = p >> LOG_FINE;   // store the "other" index, slot-sorted
    }
}

// ---------------- hop1: eraw[e,:] = (1/|e|) * sum_{v in e} xh[v,:]  (bf16, unroll-4) ----------------
__global__ __launch_bounds__(256) void gather_n2e(const int2* __restrict__ rows,
                                                  const unsigned* __restrict__ lst,
                                                  const unsigned* __restrict__ xh,
                                                  unsigned* __restrict__ eraw, int E) {
    const int sub = threadIdx.x >> 5;
    const int lane = threadIdx.x & 31;
    const int e = blockIdx.x * 8 + sub;
    if (e >= E) return;
    const int2 st = rows[e];
    const int s = st.x, t = st.y;
    float a0 = 0.f, a1 = 0.f, a2 = 0.f, a3 = 0.f;
    float c0 = 0.f, c1 = 0.f, c2 = 0.f, c3 = 0.f;
    int j = s;
    for (; j + 3 < t; j += 4) {
        const int v0 = (int)lst[j],     v1 = (int)lst[j + 1];
        const int v2 = (int)lst[j + 2], v3 = (int)lst[j + 3];
        const uint2 u0 = *(const uint2*)&xh[(size_t)v0 * 64 + lane * 2];
        const uint2 u1 = *(const uint2*)&xh[(size_t)v1 * 64 + lane * 2];
        const uint2 u2 = *(const uint2*)&xh[(size_t)v2 * 64 + lane * 2];
        const uint2 u3 = *(const uint2*)&xh[(size_t)v3 * 64 + lane * 2];
        a0 += b2f_lo(u0.x) + b2f_lo(u1.x); a1 += b2f_hi(u0.x) + b2f_hi(u1.x);
        a2 += b2f_lo(u0.y) + b2f_lo(u1.y); a3 += b2f_hi(u0.y) + b2f_hi(u1.y);
        c0 += b2f_lo(u2.x) + b2f_lo(u3.x); c1 += b2f_hi(u2.x) + b2f_hi(u3.x);
        c2 += b2f_lo(u2.y) + b2f_lo(u3.y); c3 += b2f_hi(u2.y) + b2f_hi(u3.y);
    }
    for (; j < t; ++j) {
        const uint2 u = *(const uint2*)&xh[(size_t)lst[j] * 64 + lane * 2];
        a0 += b2f_lo(u.x); a1 += b2f_hi(u.x);
        a2 += b2f_lo(u.y); a3 += b2f_hi(u.y);
    }
    a0 += c0; a1 += c1; a2 += c2; a3 += c3;
    const float binv = (t > s) ? 1.f / (float)(t - s) : 0.f;
    a0 *= binv; a1 *= binv; a2 *= binv; a3 *= binv;
    *(uint2*)&eraw[(size_t)e * 64 + lane * 2] =
        make_uint2(f2b(a0) | (f2b(a1) << 16), f2b(a2) | (f2b(a3) << 16));
}

// ---------------- mm: Out[M,128](bf16) = A[M,128](bf16) @ W[128,128](f32) ----------------
__global__ __launch_bounds__(256) void mm_kernel(const unsigned* __restrict__ A,
                                                 const float* __restrict__ W,
                                                 unsigned* __restrict__ Out, int M) {
    __shared__ float Wl[CC * CC];   // 64 KB
    __shared__ float Xl[32 * CC];   // 16 KB
    const int tid = threadIdx.x;
    for (int i = tid * 4; i < CC * CC; i += 1024) {
        *(float4*)&Wl[i] = *(const float4*)&W[i];
    }
    const int row0 = blockIdx.x * 32;
    for (int i = tid; i < 2048; i += 256) {   // 32 rows x 64 uints
        const int r = i >> 6;
        const int u = i & 63;
        const int row = row0 + r;
        const unsigned val = (row < M) ? A[(size_t)row * 64 + u] : 0u;
        Xl[r * CC + 2 * u]     = b2f_lo(val);
        Xl[r * CC + 2 * u + 1] = b2f_hi(val);
    }
    __syncthreads();
    const int c4 = (tid & 31) * 4;
    const int rg = tid >> 5;  // 0..7
    float4 acc[4];
#pragma unroll
    for (int r = 0; r < 4; ++r) acc[r] = make_float4(0.f, 0.f, 0.f, 0.f);
    for (int k4 = 0; k4 < 32; ++k4) {
        float4 xv[4];
#pragma unroll
        for (int r = 0; r < 4; ++r) xv[r] = *(const float4*)&Xl[(rg + r * 8) * CC + k4 * 4];
#pragma unroll
        for (int kk = 0; kk < 4; ++kk) {
            const float4 w = *(const float4*)&Wl[(k4 * 4 + kk) * CC + c4];
#pragma unroll
            for (int r = 0; r < 4; ++r) {
                const float xs = (&xv[r].x)[kk];
                acc[r].x += xs * w.x; acc[r].y += xs * w.y;
                acc[r].z += xs * w.z; acc[r].w += xs * w.w;
            }
        }
    }
#pragma unroll
    for (int r = 0; r < 4; ++r) {
        const int row = row0 + rg + r * 8;
        if (row < M) {
            *(uint2*)&Out[(size_t)row * 64 + (c4 >> 1)] =
                make_uint2(f2b(acc[r].x) | (f2b(acc[r].y) << 16),
                           f2b(acc[r].z) | (f2b(acc[r].w) << 16));
        }
    }
}

// ---------------- hop2 + BN stats: out = Dinv*sum efeat + b; per-channel sum/sumsq ----------------
__global__ __launch_bounds__(256) void gather_e2n_bn(const int2* __restrict__ rows,
                                                     const unsigned* __restrict__ lst,
                                                     const unsigned* __restrict__ efeat,
                                                     const float* __restrict__ hw,
                                                     const float* __restrict__ b,
                                                     float* __restrict__ out,
                                                     float* __restrict__ sums, int N) {
    __shared__ float4 red[2][8][32];   // 8 KB
    const int sub = threadIdx.x >> 5;
    const int lane = threadIdx.x & 31;
    const float4 b4 = *(const float4*)&b[lane * 4];
    float s0 = 0.f, s1 = 0.f, s2 = 0.f, s3 = 0.f;
    float q0 = 0.f, q1 = 0.f, q2 = 0.f, q3 = 0.f;
    for (int v = blockIdx.x * 8 + sub; v < N; v += gridDim.x * 8) {
        const int2 st = rows[v];
        const int s = st.x, t = st.y;
        float a0 = 0.f, a1 = 0.f, a2 = 0.f, a3 = 0.f;
        float c0 = 0.f, c1 = 0.f, c2 = 0.f, c3 = 0.f;
        float dsum = 0.f;
        int j = s;
        for (; j + 3 < t; j += 4) {
            const int e0 = (int)lst[j],     e1 = (int)lst[j + 1];
            const int e2 = (int)lst[j + 2], e3 = (int)lst[j + 3];
            const float h0 = hw[e0], h1 = hw[e1], h2 = hw[e2], h3 = hw[e3];
            const uint2 u0 = *(const uint2*)&efeat[(size_t)e0 * 64 + lane * 2];
            const uint2 u1 = *(const uint2*)&efeat[(size_t)e1 * 64 + lane * 2];
            const uint2 u2 = *(const uint2*)&efeat[(size_t)e2 * 64 + lane * 2];
            const uint2 u3 = *(const uint2*)&efeat[(size_t)e3 * 64 + lane * 2];
            dsum += (h0 + h1) + (h2 + h3);
            a0 += b2f_lo(u0.x) + b2f_lo(u1.x); a1 += b2f_hi(u0.x) + b2f_hi(u1.x);
            a2 += b2f_lo(u0.y) + b2f_lo(u1.y); a3 += b2f_hi(u0.y) + b2f_hi(u1.y);
            c0 += b2f_lo(u2.x) + b2f_lo(u3.x); c1 += b2f_hi(u2.x) + b2f_hi(u3.x);
            c2 += b2f_lo(u2.y) + b2f_lo(u3.y); c3 += b2f_hi(u2.y) + b2f_hi(u3.y);
        }
        for (; j < t; ++j) {
            const int e0 = (int)lst[j];
            dsum += hw[e0];
            const uint2 u = *(const uint2*)&efeat[(size_t)e0 * 64 + lane * 2];
            a0 += b2f_lo(u.x); a1 += b2f_hi(u.x);
            a2 += b2f_lo(u.y); a3 += b2f_hi(u.y);
        }
        a0 += c0; a1 += c1; a2 += c2; a3 += c3;
        const float dinv = (dsum > 0.f) ? 1.f / dsum : 0.f;
        float4 o;
        o.x = a0 * dinv + b4.x; o.y = a1 * dinv + b4.y;
        o.z = a2 * dinv + b4.z; o.w = a3 * dinv + b4.w;
        *(float4*)&out[(size_t)v * CC + lane * 4] = o;
        s0 += o.x; s1 += o.y; s2 += o.z; s3 += o.w;
        q0 += o.x * o.x; q1 += o.y * o.y; q2 += o.z * o.z; q3 += o.w * o.w;
    }
    red[0][sub][lane] = make_float4(s0, s1, s2, s3);
    red[1][sub][lane] = make_float4(q0, q1, q2, q3);
    __syncthreads();
    if (sub < 2) {
        float4 acc = red[sub][0][lane];
#pragma unroll
        for (int k = 1; k < 8; ++k) {
            const float4 r = red[sub][k][lane];
            acc.x += r.x; acc.y += r.y; acc.z += r.z; acc.w += r.w;
        }
        float* dst = &sums[sub * 128 + lane * 4];
        atomicAdd(&dst[0], acc.x);
        atomicAdd(&dst[1], acc.y);
        atomicAdd(&dst[2], acc.z);
        atomicAdd(&dst[3], acc.w);
    }
}

// ---------------- BN normalize + SiLU (float4) ----------------
__global__ __launch_bounds__(256) void bn_silu(float* __restrict__ out,
                                               const float* __restrict__ sums,
                                               const float* __restrict__ gamma,
                                               const float* __restrict__ beta, int N) {
    const int sub = threadIdx.x >> 5;
    const int lane = threadIdx.x & 31;
    const int c4 = lane * 4;
    const float invN = 1.0f / (float)N;
    const float4 m4 = *(const float4*)&sums[c4];
    const float4 q4 = *(const float4*)&sums[128 + c4];
    const float4 g4 = *(const float4*)&gamma[c4];
    const float4 be4 = *(const float4*)&beta[c4];
    float g[4], bb[4];
#pragma unroll
    for (int k = 0; k < 4; ++k) {
        const float mean = (&m4.x)[k] * invN;
        float var = (&q4.x)[k] * invN - mean * mean;
        var = fmaxf(var, 0.f);
        const float istd = rsqrtf(var + 1e-5f);
        g[k] = (&g4.x)[k] * istd;
        bb[k] = (&be4.x)[k] - mean * g[k];
    }
    for (int v = blockIdx.x * 8 + sub; v < N; v += gridDim.x * 8) {
        float4 y = *(const float4*)&out[(size_t)v * CC + c4];
        float z[4];
#pragma unroll
        for (int k = 0; k < 4; ++k) {
            z[k] = (&y.x)[k] * g[k] + bb[k];
            (&y.x)[k] = z[k] / (1.f + __expf(-z[k]));
        }
        *(float4*)&out[(size_t)v * CC + c4] = y;
    }
}

extern "C" void kernel_launch(void* const* d_in, const int* in_sizes, int n_in,
                              void* d_out, int out_size, void* d_ws, size_t ws_size,
                              hipStream_t stream) {
    const float* x     = (const float*)d_in[0];
    const int*   hidx  = (const int*)d_in[1];
    const float* hw    = (const float*)d_in[2];
    const float* W     = (const float*)d_in[3];
    const float* b     = (const float*)d_in[4];
    const float* gamma = (const float*)d_in[5];
    const float* beta  = (const float*)d_in[6];

    const int N   = in_sizes[0] / CC;   // 100000
    const int nnz = in_sizes[1] / 2;    // 1600000
    const int E   = in_sizes[2];        // 50000

    const int* nidx = hidx;
    const int* eidx = hidx + nnz;

    float* out = (float*)d_out;

    const int nbE = (E + FINE - 1) / FINE;   // 391
    const int nbV = (N + FINE - 1) / FINE;   // 782

    unsigned* ws      = (unsigned*)d_ws;
    unsigned* xh      = ws;                              // N*64 uints (bf16 x)
    unsigned* eraw    = xh + (size_t)N * 64;             // E*64
    unsigned* efeat   = eraw + (size_t)E * 64;           // E*64
    int2*     rowsE   = (int2*)(efeat + (size_t)E * 64); // E int2
    int2*     rowsV   = rowsE + E;                       // N int2
    float*    sums    = (float*)(rowsV + N);             // 256 floats
    int*      curE    = (int*)(sums + 256);              // nbE
    int*      curV    = curE + nbE;                      // nbV
    unsigned* binnedE = (unsigned*)(curV + nbV);         // nbE*CAPE
    unsigned* binnedV = binnedE + (size_t)nbE * CAPE;    // nbV*CAPV

    hipMemsetAsync(sums, 0, 256 * sizeof(float), stream);

    initcur<<<(nbV + 255) / 256, 256, 0, stream>>>(curE, nbE, curV, nbV);
    to_bf16<<<2048, 256, 0, stream>>>((const float4*)x, (uint2*)xh, N * CC / 4);
    bin_both<<<(nnz + BIN_TILE - 1) / BIN_TILE, 256, 0, stream>>>(
        nidx, eidx, curE, curV, binnedE, binnedV, nnz, nbE, nbV);
    fill_fine<CAPE><<<nbE, 512, 0, stream>>>(curE, binnedE, rowsE, E);
    fill_fine<CAPV><<<nbV, 512, 0, stream>>>(curV, binnedV, rowsV, N);

    gather_n2e<<<(E + 7) / 8, 256, 0, stream>>>(rowsE, binnedE, xh, eraw, E);
    mm_kernel<<<(E + 31) / 32, 256, 0, stream>>>(eraw, W, efeat, E);
    gather_e2n_bn<<<2048, 256, 0, stream>>>(rowsV, binnedV, efeat, hw, b, out, sums, N);

    bn_silu<<<1024, 256, 0, stream>>>(out, sums, gamma, beta, N);
}

// Round 7
// 292.890 us; speedup vs baseline: 1.5306x; 1.5306x over previous
//
#include <hip/hip_runtime.h>
#include <cstdint>
#include <cstddef>

#define CC 128
#define LOG_FINE 7
#define FINE 128
#define CAPE 6144     // capacity per edge bucket (mean 4092, std ~64)
#define CAPV 3072     // capacity per node bucket (mean 2046, std ~45)
#define BIN_TILE 4096 // pairs per bin_both block

__device__ __forceinline__ unsigned f2b(float f) {
    const unsigned u = __float_as_uint(f);
    return (u + 0x7fffu + ((u >> 16) & 1u)) >> 16;
}
__device__ __forceinline__ float b2f_lo(unsigned u) { return __uint_as_float(u << 16); }
__device__ __forceinline__ float b2f_hi(unsigned u) { return __uint_as_float(u & 0xffff0000u); }

// ---------------- convert f32 -> bf16 (packed 2/uint) ----------------
__global__ __launch_bounds__(256) void to_bf16(const float4* __restrict__ in,
                                               uint2* __restrict__ out, int n4) {
    for (int i = blockIdx.x * 256 + threadIdx.x; i < n4; i += gridDim.x * 256) {
        const float4 v = in[i];
        out[i] = make_uint2(f2b(v.x) | (f2b(v.y) << 16), f2b(v.z) | (f2b(v.w) << 16));
    }
}

// ---------------- init bucket cursors to region bases ----------------
__global__ __launch_bounds__(256) void initcur(int* __restrict__ curE, int nbE,
                                               int* __restrict__ curV, int nbV) {
    const int i = blockIdx.x * 256 + threadIdx.x;
    if (i < nbE) curE[i] = i * CAPE;
    if (i < nbV) curV[i] = i * CAPV;
}

// ---------------- bin pairs into fixed-capacity bucket regions (both sides) ----------------
__global__ __launch_bounds__(256) void bin_both(const int* __restrict__ nidx,
                                                const int* __restrict__ eidx,
                                                int* __restrict__ curE,
                                                int* __restrict__ curV,
                                                unsigned* __restrict__ binnedE,
                                                unsigned* __restrict__ binnedV,
                                                int nnz, int nbE, int nbV) {
    __shared__ int cntE[512], gposE[512];
    __shared__ int cntV[1024], gposV[1024];
    const int tid = threadIdx.x;
    for (int i = tid; i < nbE; i += 256) cntE[i] = 0;
    for (int i = tid; i < nbV; i += 256) cntV[i] = 0;
    __syncthreads();
    const int base = blockIdx.x * BIN_TILE;
    int pE[16], rE[16], pV[16], rV[16];
#pragma unroll
    for (int j = 0; j < 16; ++j) {
        const int i = base + tid + j * 256;
        if (i < nnz) {
            const int e = eidx[i], v = nidx[i];
            const int bE = e >> LOG_FINE, bV = v >> LOG_FINE;
            rE[j] = (bE << 16) | atomicAdd(&cntE[bE], 1);
            pE[j] = (v << LOG_FINE) | (e & (FINE - 1));
            rV[j] = (bV << 16) | atomicAdd(&cntV[bV], 1);
            pV[j] = (e << LOG_FINE) | (v & (FINE - 1));
        } else { rE[j] = -1; rV[j] = -1; }
    }
    __syncthreads();
    for (int i = tid; i < nbE; i += 256) {
        const int c = cntE[i];
        gposE[i] = (c > 0) ? atomicAdd(&curE[i], c) : 0;
    }
    for (int i = tid; i < nbV; i += 256) {
        const int c = cntV[i];
        gposV[i] = (c > 0) ? atomicAdd(&curV[i], c) : 0;
    }
    __syncthreads();
#pragma unroll
    for (int j = 0; j < 16; ++j) {
        if (rE[j] >= 0) binnedE[gposE[rE[j] >> 16] + (rE[j] & 0xffff)] = (unsigned)pE[j];
        if (rV[j] >= 0) binnedV[gposV[rV[j] >> 16] + (rV[j] & 0xffff)] = (unsigned)pV[j];
    }
}

// ---------------- E-side: per-bucket counting-sort (in place) + row ranges ----------------
__global__ __launch_bounds__(512) void fill_fineE(const int* __restrict__ cur,
                                                  unsigned* __restrict__ binned,
                                                  int2* __restrict__ rows, int nrows) {
    __shared__ unsigned vals[CAPE];
    __shared__ int scnt[FINE], soff[FINE], sscan[FINE];
    const int tid = threadIdx.x;
    const int b = blockIdx.x;
    const int base = b * CAPE;
    const int cnt = cur[b] - base;
    for (int i = tid; i < cnt; i += 512) vals[i] = binned[base + i];
    if (tid < FINE) scnt[tid] = 0;
    __syncthreads();
    for (int i = tid; i < cnt; i += 512) atomicAdd(&scnt[vals[i] & (FINE - 1)], 1);
    __syncthreads();
    if (tid < FINE) sscan[tid] = scnt[tid];
    __syncthreads();
#pragma unroll
    for (int d = 1; d < FINE; d <<= 1) {
        int t = 0;
        if (tid >= d && tid < FINE) t = sscan[tid - d];
        __syncthreads();
        if (tid < FINE) sscan[tid] += t;
        __syncthreads();
    }
    if (tid < FINE) {
        const int excl = sscan[tid] - scnt[tid];
        soff[tid] = excl;
        const int row = (b << LOG_FINE) + tid;
        if (row < nrows) rows[row] = make_int2(base + excl, base + excl + scnt[tid]);
    }
    __syncthreads();
    for (int i = tid; i < cnt; i += 512) {
        const unsigned p = vals[i];
        const int slot = (int)(p & (FINE - 1));
        const int pos = base + atomicAdd(&soff[slot], 1);
        binned[pos] = p >> LOG_FINE;
    }
}

// ---------------- V-side: counting-sort + row ranges + Dinv[v] = 1/sum(hw[e]) ----------------
__global__ __launch_bounds__(512) void fill_fineV(const int* __restrict__ cur,
                                                  unsigned* __restrict__ binned,
                                                  const float* __restrict__ hw,
                                                  int2* __restrict__ rows,
                                                  float* __restrict__ Dinv, int nrows) {
    __shared__ unsigned vals[CAPV];
    __shared__ int scnt[FINE], soff[FINE], sscan[FINE];
    __shared__ float sd[FINE];
    const int tid = threadIdx.x;
    const int b = blockIdx.x;
    const int base = b * CAPV;
    const int cnt = cur[b] - base;
    for (int i = tid; i < cnt; i += 512) vals[i] = binned[base + i];
    if (tid < FINE) { scnt[tid] = 0; sd[tid] = 0.f; }
    __syncthreads();
    for (int i = tid; i < cnt; i += 512) atomicAdd(&scnt[vals[i] & (FINE - 1)], 1);
    __syncthreads();
    if (tid < FINE) sscan[tid] = scnt[tid];
    __syncthreads();
#pragma unroll
    for (int d = 1; d < FINE; d <<= 1) {
        int t = 0;
        if (tid >= d && tid < FINE) t = sscan[tid - d];
        __syncthreads();
        if (tid < FINE) sscan[tid] += t;
        __syncthreads();
    }
    if (tid < FINE) {
        const int excl = sscan[tid] - scnt[tid];
        soff[tid] = excl;
        const int row = (b << LOG_FINE) + tid;
        if (row < nrows) rows[row] = make_int2(base + excl, base + excl + scnt[tid]);
    }
    __syncthreads();
    for (int i = tid; i < cnt; i += 512) {
        const unsigned p = vals[i];
        const int slot = (int)(p & (FINE - 1));
        const int e = (int)(p >> LOG_FINE);
        const int pos = base + atomicAdd(&soff[slot], 1);
        binned[pos] = (unsigned)e;
        atomicAdd(&sd[slot], hw[e]);
    }
    __syncthreads();
    if (tid < FINE) {
        const int row = (b << LOG_FINE) + tid;
        if (row < nrows) {
            const float d = sd[tid];
            Dinv[row] = (d > 0.f) ? 1.f / d : 0.f;
        }
    }
}

// ---------------- hop1: eraw[e,:] = (1/|e|) * sum_{v in e} xh[v,:]  (bf16, unroll-4) ----------------
__global__ __launch_bounds__(256) void gather_n2e(const int2* __restrict__ rows,
                                                  const unsigned* __restrict__ lst,
                                                  const unsigned* __restrict__ xh,
                                                  unsigned* __restrict__ eraw, int E) {
    const int sub = threadIdx.x >> 5;
    const int lane = threadIdx.x & 31;
    const int e = blockIdx.x * 8 + sub;
    if (e >= E) return;
    const int2 st = rows[e];
    const int s = st.x, t = st.y;
    float a0 = 0.f, a1 = 0.f, a2 = 0.f, a3 = 0.f;
    float c0 = 0.f, c1 = 0.f, c2 = 0.f, c3 = 0.f;
    int j = s;
    for (; j + 3 < t; j += 4) {
        const int v0 = (int)lst[j],     v1 = (int)lst[j + 1];
        const int v2 = (int)lst[j + 2], v3 = (int)lst[j + 3];
        const uint2 u0 = *(const uint2*)&xh[(size_t)v0 * 64 + lane * 2];
        const uint2 u1 = *(const uint2*)&xh[(size_t)v1 * 64 + lane * 2];
        const uint2 u2 = *(const uint2*)&xh[(size_t)v2 * 64 + lane * 2];
        const uint2 u3 = *(const uint2*)&xh[(size_t)v3 * 64 + lane * 2];
        a0 += b2f_lo(u0.x) + b2f_lo(u1.x); a1 += b2f_hi(u0.x) + b2f_hi(u1.x);
        a2 += b2f_lo(u0.y) + b2f_lo(u1.y); a3 += b2f_hi(u0.y) + b2f_hi(u1.y);
        c0 += b2f_lo(u2.x) + b2f_lo(u3.x); c1 += b2f_hi(u2.x) + b2f_hi(u3.x);
        c2 += b2f_lo(u2.y) + b2f_lo(u3.y); c3 += b2f_hi(u2.y) + b2f_hi(u3.y);
    }
    for (; j < t; ++j) {
        const uint2 u = *(const uint2*)&xh[(size_t)lst[j] * 64 + lane * 2];
        a0 += b2f_lo(u.x); a1 += b2f_hi(u.x);
        a2 += b2f_lo(u.y); a3 += b2f_hi(u.y);
    }
    a0 += c0; a1 += c1; a2 += c2; a3 += c3;
    const float binv = (t > s) ? 1.f / (float)(t - s) : 0.f;
    a0 *= binv; a1 *= binv; a2 *= binv; a3 *= binv;
    *(uint2*)&eraw[(size_t)e * 64 + lane * 2] =
        make_uint2(f2b(a0) | (f2b(a1) << 16), f2b(a2) | (f2b(a3) << 16));
}

// ---------------- mm: Out[M,128](bf16) = A[M,128](bf16) @ W[128,128](f32) ----------------
__global__ __launch_bounds__(256) void mm_kernel(const unsigned* __restrict__ A,
                                                 const float* __restrict__ W,
                                                 unsigned* __restrict__ Out, int M) {
    __shared__ float Wl[CC * CC];   // 64 KB
    __shared__ float Xl[32 * CC];   // 16 KB
    const int tid = threadIdx.x;
    for (int i = tid * 4; i < CC * CC; i += 1024) {
        *(float4*)&Wl[i] = *(const float4*)&W[i];
    }
    const int row0 = blockIdx.x * 32;
    for (int i = tid; i < 2048; i += 256) {   // 32 rows x 64 uints
        const int r = i >> 6;
        const int u = i & 63;
        const int row = row0 + r;
        const unsigned val = (row < M) ? A[(size_t)row * 64 + u] : 0u;
        Xl[r * CC + 2 * u]     = b2f_lo(val);
        Xl[r * CC + 2 * u + 1] = b2f_hi(val);
    }
    __syncthreads();
    const int c4 = (tid & 31) * 4;
    const int rg = tid >> 5;  // 0..7
    float4 acc[4];
#pragma unroll
    for (int r = 0; r < 4; ++r) acc[r] = make_float4(0.f, 0.f, 0.f, 0.f);
    for (int k4 = 0; k4 < 32; ++k4) {
        float4 xv[4];
#pragma unroll
        for (int r = 0; r < 4; ++r) xv[r] = *(const float4*)&Xl[(rg + r * 8) * CC + k4 * 4];
#pragma unroll
        for (int kk = 0; kk < 4; ++kk) {
            const float4 w = *(const float4*)&Wl[(k4 * 4 + kk) * CC + c4];
#pragma unroll
            for (int r = 0; r < 4; ++r) {
                const float xs = (&xv[r].x)[kk];
                acc[r].x += xs * w.x; acc[r].y += xs * w.y;
                acc[r].z += xs * w.z; acc[r].w += xs * w.w;
            }
        }
    }
#pragma unroll
    for (int r = 0; r < 4; ++r) {
        const int row = row0 + rg + r * 8;
        if (row < M) {
            *(uint2*)&Out[(size_t)row * 64 + (c4 >> 1)] =
                make_uint2(f2b(acc[r].x) | (f2b(acc[r].y) << 16),
                           f2b(acc[r].z) | (f2b(acc[r].w) << 16));
        }
    }
}

// ---------------- hop2: out[v,:] = Dinv[v] * sum_{e ni v} efeat[e,:] + b  (bf16, unroll-4) ----------------
__global__ __launch_bounds__(256) void gather_e2n(const int2* __restrict__ rows,
                                                  const unsigned* __restrict__ lst,
                                                  const unsigned* __restrict__ efeat,
                                                  const float* __restrict__ Dinv,
                                                  const float* __restrict__ b,
                                                  float* __restrict__ out, int N) {
    const int sub = threadIdx.x >> 5;
    const int lane = threadIdx.x & 31;
    const int v = blockIdx.x * 8 + sub;
    if (v >= N) return;
    const int2 st = rows[v];
    const int s = st.x, t = st.y;
    float a0 = 0.f, a1 = 0.f, a2 = 0.f, a3 = 0.f;
    float c0 = 0.f, c1 = 0.f, c2 = 0.f, c3 = 0.f;
    int j = s;
    for (; j + 3 < t; j += 4) {
        const int e0 = (int)lst[j],     e1 = (int)lst[j + 1];
        const int e2 = (int)lst[j + 2], e3 = (int)lst[j + 3];
        const uint2 u0 = *(const uint2*)&efeat[(size_t)e0 * 64 + lane * 2];
        const uint2 u1 = *(const uint2*)&efeat[(size_t)e1 * 64 + lane * 2];
        const uint2 u2 = *(const uint2*)&efeat[(size_t)e2 * 64 + lane * 2];
        const uint2 u3 = *(const uint2*)&efeat[(size_t)e3 * 64 + lane * 2];
        a0 += b2f_lo(u0.x) + b2f_lo(u1.x); a1 += b2f_hi(u0.x) + b2f_hi(u1.x);
        a2 += b2f_lo(u0.y) + b2f_lo(u1.y); a3 += b2f_hi(u0.y) + b2f_hi(u1.y);
        c0 += b2f_lo(u2.x) + b2f_lo(u3.x); c1 += b2f_hi(u2.x) + b2f_hi(u3.x);
        c2 += b2f_lo(u2.y) + b2f_lo(u3.y); c3 += b2f_hi(u2.y) + b2f_hi(u3.y);
    }
    for (; j < t; ++j) {
        const uint2 u = *(const uint2*)&efeat[(size_t)lst[j] * 64 + lane * 2];
        a0 += b2f_lo(u.x); a1 += b2f_hi(u.x);
        a2 += b2f_lo(u.y); a3 += b2f_hi(u.y);
    }
    a0 += c0; a1 += c1; a2 += c2; a3 += c3;
    const float dinv = Dinv[v];
    const float4 b4 = *(const float4*)&b[lane * 4];
    float4 o;
    o.x = a0 * dinv + b4.x; o.y = a1 * dinv + b4.y;
    o.z = a2 * dinv + b4.z; o.w = a3 * dinv + b4.w;
    *(float4*)&out[(size_t)v * CC + lane * 4] = o;
}

// ---------------- BN stats: per-channel sum & sumsq (read-only) ----------------
__global__ __launch_bounds__(512) void bn_stats(const float* __restrict__ out,
                                                float* __restrict__ sums, int N) {
    __shared__ float reds[512];
    __shared__ float redq[512];
    const int c = threadIdx.x & 127;
    const int rg = threadIdx.x >> 7;  // 0..3
    float s = 0.f, sq = 0.f;
    for (int v = blockIdx.x * 4 + rg; v < N; v += gridDim.x * 4) {
        const float y = out[(size_t)v * CC + c];
        s += y; sq += y * y;
    }
    reds[threadIdx.x] = s;
    redq[threadIdx.x] = sq;
    __syncthreads();
    if (rg == 0) {
        const float ts = reds[c] + reds[128 + c] + reds[256 + c] + reds[384 + c];
        const float tq = redq[c] + redq[128 + c] + redq[256 + c] + redq[384 + c];
        atomicAdd(&sums[c], ts);
        atomicAdd(&sums[CC + c], tq);
    }
}

// ---------------- BN normalize + SiLU (float4) ----------------
__global__ __launch_bounds__(256) void bn_silu(float* __restrict__ out,
                                               const float* __restrict__ sums,
                                               const float* __restrict__ gamma,
                                               const float* __restrict__ beta, int N) {
    const int sub = threadIdx.x >> 5;
    const int lane = threadIdx.x & 31;
    const int c4 = lane * 4;
    const float invN = 1.0f / (float)N;
    const float4 m4 = *(const float4*)&sums[c4];
    const float4 q4 = *(const float4*)&sums[128 + c4];
    const float4 g4 = *(const float4*)&gamma[c4];
    const float4 be4 = *(const float4*)&beta[c4];
    float g[4], bb[4];
#pragma unroll
    for (int k = 0; k < 4; ++k) {
        const float mean = (&m4.x)[k] * invN;
        float var = (&q4.x)[k] * invN - mean * mean;
        var = fmaxf(var, 0.f);
        const float istd = rsqrtf(var + 1e-5f);
        g[k] = (&g4.x)[k] * istd;
        bb[k] = (&be4.x)[k] - mean * g[k];
    }
    for (int v = blockIdx.x * 8 + sub; v < N; v += gridDim.x * 8) {
        float4 y = *(const float4*)&out[(size_t)v * CC + c4];
        float z[4];
#pragma unroll
        for (int k = 0; k < 4; ++k) {
            z[k] = (&y.x)[k] * g[k] + bb[k];
            (&y.x)[k] = z[k] / (1.f + __expf(-z[k]));
        }
        *(float4*)&out[(size_t)v * CC + c4] = y;
    }
}

extern "C" void kernel_launch(void* const* d_in, const int* in_sizes, int n_in,
                              void* d_out, int out_size, void* d_ws, size_t ws_size,
                              hipStream_t stream) {
    const float* x     = (const float*)d_in[0];
    const int*   hidx  = (const int*)d_in[1];
    const float* hw    = (const float*)d_in[2];
    const float* W     = (const float*)d_in[3];
    const float* b     = (const float*)d_in[4];
    const float* gamma = (const float*)d_in[5];
    const float* beta  = (const float*)d_in[6];

    const int N   = in_sizes[0] / CC;   // 100000
    const int nnz = in_sizes[1] / 2;    // 1600000
    const int E   = in_sizes[2];        // 50000

    const int* nidx = hidx;
    const int* eidx = hidx + nnz;

    float* out = (float*)d_out;

    const int nbE = (E + FINE - 1) / FINE;   // 391
    const int nbV = (N + FINE - 1) / FINE;   // 782

    unsigned* ws      = (unsigned*)d_ws;
    unsigned* xh      = ws;                              // N*64 uints (bf16 x)
    unsigned* eraw    = xh + (size_t)N * 64;             // E*64
    unsigned* efeat   = eraw + (size_t)E * 64;           // E*64
    int2*     rowsE   = (int2*)(efeat + (size_t)E * 64); // E int2
    int2*     rowsV   = rowsE + E;                       // N int2
    float*    Dinv    = (float*)(rowsV + N);             // N floats
    float*    sums    = Dinv + N;                        // 256 floats
    int*      curE    = (int*)(sums + 256);              // nbE
    int*      curV    = curE + nbE;                      // nbV
    unsigned* binnedE = (unsigned*)(curV + nbV);         // nbE*CAPE
    unsigned* binnedV = binnedE + (size_t)nbE * CAPE;    // nbV*CAPV

    hipMemsetAsync(sums, 0, 256 * sizeof(float), stream);

    initcur<<<(nbV + 255) / 256, 256, 0, stream>>>(curE, nbE, curV, nbV);
    to_bf16<<<2048, 256, 0, stream>>>((const float4*)x, (uint2*)xh, N * CC / 4);
    bin_both<<<(nnz + BIN_TILE - 1) / BIN_TILE, 256, 0, stream>>>(
        nidx, eidx, curE, curV, binnedE, binnedV, nnz, nbE, nbV);
    fill_fineE<<<nbE, 512, 0, stream>>>(curE, binnedE, rowsE, E);
    fill_fineV<<<nbV, 512, 0, stream>>>(curV, binnedV, hw, rowsV, Dinv, N);

    gather_n2e<<<(E + 7) / 8, 256, 0, stream>>>(rowsE, binnedE, xh, eraw, E);
    mm_kernel<<<(E + 31) / 32, 256, 0, stream>>>(eraw, W, efeat, E);
    gather_e2n<<<(N + 7) / 8, 256, 0, stream>>>(rowsV, binnedV, efeat, Dinv, b, out, N);

    bn_stats<<<512, 512, 0, stream>>>(out, sums, N);
    bn_silu<<<1024, 256, 0, stream>>>(out, sums, gamma, beta, N);
}